// Round 3
// baseline (293.035 us; speedup 1.0000x reference)
//
#include <hip/hip_runtime.h>

#define NHEADS 8
#define TQ 4
#define QH 16
#define QW 16
#define TK 4
#define KH 16
#define KW 16
#define DIM 64
#define BATCH 4

#define ROWS (BATCH * NHEADS * TQ * QH * QW)   // 32768
#define RELSTRIDE 40                            // 36 bias values, padded to 40 floats (160 B)

// ---------------- Kernel A: bias precompute ----------------
// One thread per (row, j) dot; j in [0,36). Writes rel[row][j]:
//   j<16 : dot(q_row, hemb[h-j+15])         (rel_h for kh=j)
//   j<32 : dot(q_row, wemb[w-(j-16)+15])    (rel_w for kw=j-16)
//   else : dot(q_row, temb[t-(j-32)+3])     (rel_t for tk=j-32)
__global__ __launch_bounds__(256) void bias_kernel(
    const float* __restrict__ query,   // [ROWS,64]
    const float* __restrict__ hemb,    // [31,64]
    const float* __restrict__ wemb,    // [31,64]
    const float* __restrict__ temb,    // [7,64]
    float* __restrict__ relbuf)        // [ROWS,RELSTRIDE]
{
    const int g = blockIdx.x * 256 + threadIdx.x;
    if (g >= ROWS * 36) return;
    const int row = g / 36;
    const int j = g - row * 36;

    const int pos = row & 1023;
    const int t = pos >> 8;
    const int h = (pos >> 4) & 15;
    const int w = pos & 15;

    const float* emb;
    int e;
    if (j < 16)      { emb = hemb; e = h - j + 15; }
    else if (j < 32) { emb = wemb; e = w - (j - 16) + 15; }
    else             { emb = temb; e = t - (j - 32) + 3; }

    const float4* e4 = (const float4*)(emb + (size_t)e * DIM);
    const float4* q4 = (const float4*)(query + (size_t)row * DIM);
    float acc = 0.f;
#pragma unroll
    for (int c = 0; c < DIM / 4; ++c) {
        float4 qv = q4[c];
        float4 ev = e4[c];
        acc += qv.x * ev.x + qv.y * ev.y + qv.z * ev.z + qv.w * ev.w;
    }
    relbuf[(size_t)row * RELSTRIDE + j] = acc;
}

// ---------------- Kernel B: pure stream add ----------------
// Grid-stride over all float4s of scores/out. No barriers, no LDS.
#define BBLOCKS 2048
__global__ __launch_bounds__(256) void stream_kernel(
    const float* __restrict__ scores,
    const float* __restrict__ relbuf,
    float* __restrict__ out)
{
    const int total4 = ROWS * 256;               // 8388608 float4s
    const int stride = BBLOCKS * 256;            // 524288 threads -> 16 float4/thread
    const float4* sc4 = (const float4*)scores;
    float4* o4 = (float4*)out;

    int f0 = blockIdx.x * 256 + threadIdx.x;
#pragma unroll
    for (int i = 0; i < 4; ++i) {
        int f[4];
        float4 s[4], wv[4];
        float a[4];
#pragma unroll
        for (int k = 0; k < 4; ++k) {
            f[k] = f0 + (4 * i + k) * stride;
            const int sub = f[k] & 255;          // float4 index within row
            const int row = f[k] >> 8;
            const int tk  = sub >> 6;
            const int kh  = (sub >> 2) & 15;
            const int kw0 = (sub & 3) << 2;
            const float* rel = relbuf + (size_t)row * RELSTRIDE;
            s[k]  = sc4[f[k]];
            wv[k] = *(const float4*)(rel + 16 + kw0);
            a[k]  = rel[kh] + rel[32 + tk];
        }
#pragma unroll
        for (int k = 0; k < 4; ++k) {
            float4 o;
            o.x = s[k].x + a[k] + wv[k].x;
            o.y = s[k].y + a[k] + wv[k].y;
            o.z = s[k].z + a[k] + wv[k].z;
            o.w = s[k].w + a[k] + wv[k].w;
            o4[f[k]] = o;
        }
    }
    (void)total4;
}

// ---------------- Fallback (round-2 kernel) if ws too small ----------------
__global__ __launch_bounds__(256) void relpos_fallback(
    const float* __restrict__ query, const float* __restrict__ scores,
    const float* __restrict__ hemb, const float* __restrict__ wemb,
    const float* __restrict__ temb, float* __restrict__ out)
{
    const int tid  = threadIdx.x;
    const int row0 = blockIdx.x << 2;
    const int pos  = row0 & 1023;
    const int t  = pos >> 8;
    const int h  = (pos >> 4) & 15;
    const int w0 = pos & 15;

    const float4* sc4 = (const float4*)(scores + (size_t)row0 * 1024);
    float4 s0 = sc4[tid], s1 = sc4[256 + tid], s2 = sc4[512 + tid], s3 = sc4[768 + tid];

    __shared__ float rel[4][36];
    if (tid < 144) {
        const int r = tid / 36;
        const int j = tid - r * 36;
        const float* emb; int e;
        if (j < 16)      { emb = hemb; e = h - j + 15; }
        else if (j < 32) { emb = wemb; e = (w0 + r) - (j - 16) + 15; }
        else             { emb = temb; e = t - (j - 32) + 3; }
        const float4* e4 = (const float4*)(emb + (size_t)e * DIM);
        const float4* q4 = (const float4*)(query + (size_t)(row0 + r) * DIM);
        float acc = 0.f;
#pragma unroll
        for (int c = 0; c < DIM / 4; ++c) {
            float4 qv = q4[c]; float4 ev = e4[c];
            acc += qv.x * ev.x + qv.y * ev.y + qv.z * ev.z + qv.w * ev.w;
        }
        rel[r][j] = acc;
    }
    __syncthreads();

    const int base = tid << 2;
    const int tk = base >> 8, kh = (base >> 4) & 15, kw0 = base & 15;
    float4* o4 = (float4*)(out + (size_t)row0 * 1024);
#pragma unroll
    for (int r = 0; r < 4; ++r) {
        const float4 s = (r == 0) ? s0 : (r == 1) ? s1 : (r == 2) ? s2 : s3;
        const float a = rel[r][kh] + rel[r][32 + tk];
        float4 o;
        o.x = s.x + a + rel[r][16 + kw0 + 0];
        o.y = s.y + a + rel[r][16 + kw0 + 1];
        o.z = s.z + a + rel[r][16 + kw0 + 2];
        o.w = s.w + a + rel[r][16 + kw0 + 3];
        o4[r * 256 + tid] = o;
    }
}

extern "C" void kernel_launch(void* const* d_in, const int* in_sizes, int n_in,
                              void* d_out, int out_size, void* d_ws, size_t ws_size,
                              hipStream_t stream) {
    const float* query  = (const float*)d_in[0];
    const float* scores = (const float*)d_in[1];
    const float* hemb   = (const float*)d_in[2];
    const float* wemb   = (const float*)d_in[3];
    const float* temb   = (const float*)d_in[4];
    float* out = (float*)d_out;

    const size_t need = (size_t)ROWS * RELSTRIDE * sizeof(float);  // 5.24 MB
    if (ws_size >= need) {
        float* relbuf = (float*)d_ws;
        const int adots = ROWS * 36;
        bias_kernel<<<dim3((adots + 255) / 256), dim3(256), 0, stream>>>(
            query, hemb, wemb, temb, relbuf);
        stream_kernel<<<dim3(BBLOCKS), dim3(256), 0, stream>>>(scores, relbuf, out);
    } else {
        relpos_fallback<<<dim3(ROWS / 4), dim3(256), 0, stream>>>(
            query, scores, hemb, wemb, temb, out);
    }
}

// Round 5
// 258.043 us; speedup vs baseline: 1.1356x; 1.1356x over previous
//
#include <hip/hip_runtime.h>

#define NHEADS 8
#define TQ 4
#define QH 16
#define QW 16
#define TK 4
#define KH 16
#define KW 16
#define DIM 64
#define BATCH 4
#define ROWS (BATCH * NHEADS * TQ * QH * QW)   // 32768

typedef float f4 __attribute__((ext_vector_type(4)));   // native vector: nt-builtin compatible

// One WAVE per q-row, 4 rows per 256-thread block. No __syncthreads:
// each wave computes its own row's 36 bias dots (lanes 0..35) into LDS and
// reads them back (same-wave DS ordering + wave_barrier). Score loads are
// prefetched nontemporally before the dot; stores are nontemporal.
__global__ __launch_bounds__(256) void relpos_fused(
    const float* __restrict__ query,   // [ROWS,64]
    const float* __restrict__ scores,  // [ROWS,1024]
    const float* __restrict__ hemb,    // [31,64]
    const float* __restrict__ wemb,    // [31,64]
    const float* __restrict__ temb,    // [7,64]
    float* __restrict__ out)           // [ROWS,1024]
{
    const int lane = threadIdx.x & 63;
    const int wid  = threadIdx.x >> 6;          // wave 0..3
    const int row  = (blockIdx.x << 2) + wid;
    const int pos  = row & 1023;
    const int t = pos >> 8;
    const int h = (pos >> 4) & 15;
    const int w = pos & 15;

    // ---- Phase 0: issue the row's 1024 score floats (4 f4/lane, nt) ----
    const f4* sc4 = (const f4*)(scores + (size_t)row * 1024);
    f4 s0 = __builtin_nontemporal_load(&sc4[lane]);
    f4 s1 = __builtin_nontemporal_load(&sc4[64 + lane]);
    f4 s2 = __builtin_nontemporal_load(&sc4[128 + lane]);
    f4 s3 = __builtin_nontemporal_load(&sc4[192 + lane]);

    // ---- Phase 1: lanes 0..35 compute bias dots (q and emb are L1/L2-hot) ----
    __shared__ float rel[4][40];   // [wave][0:16)=rel_h, [16:32)=rel_w, [32:36)=rel_t
    if (lane < 36) {
        const float* emb;
        int e;
        if (lane < 16)      { emb = hemb; e = h - lane + 15; }
        else if (lane < 32) { emb = wemb; e = w - (lane - 16) + 15; }
        else                { emb = temb; e = t - (lane - 32) + 3; }
        const f4* e4 = (const f4*)(emb + (size_t)e * DIM);
        const f4* q4 = (const f4*)(query + (size_t)row * DIM);
        float a0 = 0.f, a1 = 0.f, a2 = 0.f, a3 = 0.f;
#pragma unroll
        for (int c = 0; c < DIM / 4; c += 4) {
            f4 qa = q4[c + 0], ea = e4[c + 0];
            f4 qb = q4[c + 1], eb = e4[c + 1];
            f4 qc = q4[c + 2], ec = e4[c + 2];
            f4 qd = q4[c + 3], ed = e4[c + 3];
            a0 += qa.x * ea.x + qa.y * ea.y + qa.z * ea.z + qa.w * ea.w;
            a1 += qb.x * eb.x + qb.y * eb.y + qb.z * eb.z + qb.w * eb.w;
            a2 += qc.x * ec.x + qc.y * ec.y + qc.z * ec.z + qc.w * ec.w;
            a3 += qd.x * ed.x + qd.y * ed.y + qd.z * ed.z + qd.w * ed.w;
        }
        rel[wid][lane] = (a0 + a1) + (a2 + a3);
    }
    __builtin_amdgcn_wave_barrier();   // pin DS write-before-read ordering (free)

    // ---- Phase 2: combine + nt store. Lane's float4 j = 64c+lane, c=tk. ----
    // kh = lane>>2 and kw0 = (lane&3)<<2 are chunk-invariant:
    // 3 LDS reads total per lane for the whole row.
    const int kh  = lane >> 2;
    const int kw0 = (lane & 3) << 2;
    const float bh = rel[wid][kh];
    const f4 bw = *(const f4*)&rel[wid][16 + kw0];
    const f4 bt = *(const f4*)&rel[wid][32];   // rel_t[0..3]

    f4* o4 = (f4*)(out + (size_t)row * 1024);
    {
        const float a = bh + bt.x;
        f4 o = s0 + a;  o += bw;
        __builtin_nontemporal_store(o, &o4[lane]);
    }
    {
        const float a = bh + bt.y;
        f4 o = s1 + a;  o += bw;
        __builtin_nontemporal_store(o, &o4[64 + lane]);
    }
    {
        const float a = bh + bt.z;
        f4 o = s2 + a;  o += bw;
        __builtin_nontemporal_store(o, &o4[128 + lane]);
    }
    {
        const float a = bh + bt.w;
        f4 o = s3 + a;  o += bw;
        __builtin_nontemporal_store(o, &o4[192 + lane]);
    }
}

extern "C" void kernel_launch(void* const* d_in, const int* in_sizes, int n_in,
                              void* d_out, int out_size, void* d_ws, size_t ws_size,
                              hipStream_t stream) {
    const float* query  = (const float*)d_in[0];
    const float* scores = (const float*)d_in[1];
    const float* hemb   = (const float*)d_in[2];
    const float* wemb   = (const float*)d_in[3];
    const float* temb   = (const float*)d_in[4];
    float* out = (float*)d_out;

    relpos_fused<<<dim3(ROWS / 4), dim3(256), 0, stream>>>(
        query, scores, hemb, wemb, temb, out);
}